// Round 20
// baseline (165.305 us; speedup 1.0000x reference)
//
#include <hip/hip_runtime.h>
#include <stdint.h>

typedef __attribute__((ext_vector_type(8))) short short8;
typedef __attribute__((ext_vector_type(4))) short short4v;
typedef __attribute__((ext_vector_type(4))) float floatx4;
typedef __attribute__((ext_vector_type(16))) float floatx16;

#define QSCALE 0.1803368801111f /* 0.125 * log2(e): S in log2 units */

__device__ __forceinline__ unsigned short f2bf(float f) {
  unsigned int u = __float_as_uint(f);
  unsigned int r = (u + 0x7FFFu + ((u >> 16) & 1u)) >> 16;  // RNE
  return (unsigned short)r;
}

__device__ __forceinline__ unsigned int cvt_pk_bf16(float lo, float hi) {
  unsigned int r;
  asm("v_cvt_pk_bf16_f32 %0, %1, %2" : "=v"(r) : "v"(lo), "v"(hi));
  return r;
}

__device__ __forceinline__ float max3f(float a, float b, float c) {
  float r;
  asm("v_max3_f32 %0, %1, %2, %3" : "=v"(r) : "v"(a), "v"(b), "v"(c));
  return r;
}

__device__ __forceinline__ void async_copy16(void* lds, const void* g) {
  __builtin_amdgcn_global_load_lds(
      (const __attribute__((address_space(1))) unsigned int*)g,
      (__attribute__((address_space(3))) unsigned int*)lds, 16, 0, 0);
}

// ---------------------------------------------------------------------------
// ALL fp32 -> bf16 conversions in one launch.
// ---------------------------------------------------------------------------
__global__ __launch_bounds__(256) void f2ball_kernel(
    const float* __restrict__ x, unsigned short* __restrict__ xb,
    const float* __restrict__ w0, const float* __restrict__ w1,
    const float* __restrict__ w2, const float* __restrict__ w3,
    unsigned short* __restrict__ o0, unsigned short* __restrict__ o1,
    unsigned short* __restrict__ o2, unsigned short* __restrict__ o3) {
  const float* in;
  unsigned short* out;
  long i;
  if (blockIdx.x < 8192) {
    in = x;
    out = xb;
    i = (long)blockIdx.x * 256 + threadIdx.x;
  } else {
    int wb = blockIdx.x - 8192;
    int which = wb >> 10;
    in = (which == 0) ? w0 : (which == 1) ? w1 : (which == 2) ? w2 : w3;
    out = (which == 0) ? o0 : (which == 1) ? o1 : (which == 2) ? o2 : o3;
    i = (long)(wb & 1023) * 256 + threadIdx.x;
  }
  float4 v = ((const float4*)in)[i];
  short4v o;
  o[0] = (short)f2bf(v.x);
  o[1] = (short)f2bf(v.y);
  o[2] = (short)f2bf(v.z);
  o[3] = (short)f2bf(v.w);
  *(short4v*)(out + i * 4) = o;
}

// ===========================================================================
// 128x256 double-buffered GEMM mainloop (shared by qkv256 / out256).
// As [2][128][32], Bs [2][256][32]; 48 KB LDS total; 1 barrier per K-step.
// Each wave computes a 64x128 sub-tile: acc[4][8].
// ===========================================================================
__device__ __forceinline__ void gemm256_mainloop(
    const unsigned short* __restrict__ A, const unsigned short* __restrict__ Bt,
    long brow, long bcol, unsigned short* As, unsigned short* Bs,
    floatx4 acc[4][8]) {
  const int tid = threadIdx.x;
  const int wave = tid >> 6, lane = tid & 63;
  const int wr = wave >> 1, wc = wave & 1;
  const int lr = lane & 15, lg = lane >> 4;
  const int K = 1024;

  const unsigned short* ga = A + (brow + (tid >> 2)) * (long)K + (tid & 3) * 8;
  const unsigned short* gb = Bt + (bcol + (tid >> 2)) * (long)K + (tid & 3) * 8;
  const int woff = wave * 512;
  const int a_off = (wr * 64 + lr) * 32 + lg * 8;
  const int b_off = (wc * 128 + lr) * 32 + lg * 8;

  async_copy16(As + woff, ga);
  async_copy16(As + woff + 2048, ga + (long)64 * K);
#pragma unroll
  for (int jj = 0; jj < 4; ++jj)
    async_copy16(Bs + woff + jj * 2048, gb + (long)jj * 64 * K);
  ga += 32;
  gb += 32;
  __syncthreads();

  int buf = 0;
  for (int kt = 0; kt < K; kt += 32) {
    if (kt + 32 < K) {
      unsigned short* lA = As + (buf ^ 1) * 4096 + woff;
      unsigned short* lB = Bs + (buf ^ 1) * 8192 + woff;
      async_copy16(lA, ga);
      async_copy16(lA + 2048, ga + (long)64 * K);
#pragma unroll
      for (int jj = 0; jj < 4; ++jj)
        async_copy16(lB + jj * 2048, gb + (long)jj * 64 * K);
      ga += 32;
      gb += 32;
    }
    const unsigned short* Ab = As + buf * 4096;
    const unsigned short* Bb = Bs + buf * 8192;
    short8 av[4], bvf[8];
#pragma unroll
    for (int i = 0; i < 4; ++i) av[i] = *(const short8*)(Ab + a_off + i * 512);
#pragma unroll
    for (int j = 0; j < 8; ++j) bvf[j] = *(const short8*)(Bb + b_off + j * 512);
    __builtin_amdgcn_s_setprio(1);
#pragma unroll
    for (int i = 0; i < 4; ++i)
#pragma unroll
      for (int j = 0; j < 8; ++j)
        acc[i][j] = __builtin_amdgcn_mfma_f32_16x16x32_bf16(av[i], bvf[j], acc[i][j], 0, 0, 0);
    __builtin_amdgcn_s_setprio(0);
    __syncthreads();
    buf ^= 1;
  }
}

// ---------------------------------------------------------------------------
// QKV projection, 128x256 tile. Q pre-scaled to log2 units; V-epilogue
// transposes via LDS in two 128-col halves. Grid (64,12), 48 KB LDS.
// ---------------------------------------------------------------------------
__global__ __launch_bounds__(256, 2) void qkv_gemm256(
    const unsigned short* __restrict__ xb, const unsigned short* __restrict__ wqkv,
    const float* __restrict__ bq, const float* __restrict__ bk,
    const float* __restrict__ bv, unsigned short* __restrict__ q_out,
    unsigned short* __restrict__ k_out, unsigned short* __restrict__ vt_out) {
  __shared__ __align__(16) unsigned short Sh[24576];  // 48 KB
  unsigned short* As = Sh;
  unsigned short* Bs = Sh + 8192;

  const int tid = threadIdx.x;
  const int wave = tid >> 6, lane = tid & 63;
  const int wr = wave >> 1, wc = wave & 1;
  const int lr = lane & 15, lg = lane >> 4;

  const long brow = (long)blockIdx.x * 128;
  const long bcol = (long)blockIdx.y * 256;

  floatx4 zero = {0.f, 0.f, 0.f, 0.f};
  floatx4 acc[4][8];
#pragma unroll
  for (int i = 0; i < 4; ++i)
#pragma unroll
    for (int j = 0; j < 8; ++j) acc[i][j] = zero;

  gemm256_mainloop(xb, wqkv, brow, bcol, As, Bs, acc);

  const int kind = (int)(bcol >> 10);
  const float* bias = (kind == 0) ? bq : (kind == 1 ? bk : bv);

  if (kind == 2) {
#pragma unroll 1
    for (int half = 0; half < 2; ++half) {
      if (wc == half) {
#pragma unroll
        for (int i = 0; i < 4; ++i)
#pragma unroll
          for (int j = 0; j < 8; ++j) {
            int n_local = j * 16 + lr;
            int m_base = wr * 64 + i * 16 + lg * 4;
            float bsc = bias[(int)((bcol + half * 128 + n_local) & 1023)];
            short4v pk;
#pragma unroll
            for (int r = 0; r < 4; ++r) pk[r] = (short)f2bf(acc[i][j][r] + bsc);
            *(short4v*)(Sh + n_local * 136 + m_base) = pk;
          }
      }
      __syncthreads();
      const int b = (int)(brow >> 11);
      const int t0 = (int)(brow & 2047);
      const int f0h = (int)(bcol - 2048) + half * 128;
#pragma unroll
      for (int p = 0; p < 8; ++p) {
        int c = p * 256 + tid;
        int d_loc = c >> 4, tc = c & 15;
        short8 v = *(const short8*)(Sh + d_loc * 136 + tc * 8);
        int h = (f0h >> 6) + (d_loc >> 6);
        int d = d_loc & 63;
        *(short8*)(vt_out + ((long)((b * 16 + h) * 64 + d)) * 2048 + t0 + tc * 8) = v;
      }
      __syncthreads();
    }
  } else {
#pragma unroll
    for (int i = 0; i < 4; ++i)
#pragma unroll
      for (int j = 0; j < 8; ++j)
#pragma unroll
        for (int r = 0; r < 4; ++r) {
          int m = (int)brow + wr * 64 + i * 16 + lg * 4 + r;
          int n = (int)bcol + wc * 128 + j * 16 + lr;
          int f = n & 1023;
          float v = acc[i][j][r] + bias[f];
          if (kind == 0) v *= QSCALE;
          unsigned short o = f2bf(v);
          int h = f >> 6, d = f & 63;
          int bb = m >> 11, t = m & 2047;
          long bh = (long)(bb * 16 + h);
          if (kind == 0)
            q_out[(bh * 2048 + t) * 64 + d] = o;
          else
            k_out[(bh * 2048 + t) * 64 + d] = o;
        }
  }
}

// ---------------------------------------------------------------------------
// Output projection, 128x256 tile. Grid (64,4), fp32 + bias epilogue.
// ---------------------------------------------------------------------------
__global__ __launch_bounds__(256, 2) void out_gemm256(
    const unsigned short* __restrict__ ob, const unsigned short* __restrict__ wo,
    const float* __restrict__ bo, float* __restrict__ out) {
  __shared__ __align__(16) unsigned short Sh[24576];  // 48 KB
  unsigned short* As = Sh;
  unsigned short* Bs = Sh + 8192;

  const int tid = threadIdx.x;
  const int wave = tid >> 6, lane = tid & 63;
  const int wr = wave >> 1, wc = wave & 1;
  const int lr = lane & 15, lg = lane >> 4;

  const long brow = (long)blockIdx.x * 128;
  const long bcol = (long)blockIdx.y * 256;

  floatx4 zero = {0.f, 0.f, 0.f, 0.f};
  floatx4 acc[4][8];
#pragma unroll
  for (int i = 0; i < 4; ++i)
#pragma unroll
    for (int j = 0; j < 8; ++j) acc[i][j] = zero;

  gemm256_mainloop(ob, wo, brow, bcol, As, Bs, acc);

#pragma unroll
  for (int i = 0; i < 4; ++i)
#pragma unroll
    for (int j = 0; j < 8; ++j)
#pragma unroll
      for (int r = 0; r < 4; ++r) {
        int m = (int)brow + wr * 64 + i * 16 + lg * 4 + r;
        int n = (int)bcol + wc * 128 + j * 16 + lr;
        out[(long)m * 1024 + n] = acc[i][j][r] + bo[n];
      }
}

// ---------------------------------------------------------------------------
// Flash attention v13: 4 waves x 32 q-rows, 32x32 swapped-QK in-register
// softmax, KVBLK=64 dbuf (32 KB LDS), l-via-MFMA(ones), 1024-block LPT grid.
// ---------------------------------------------------------------------------
__device__ __forceinline__ void stage_kv(char* __restrict__ Kb, char* __restrict__ Vb,
                                         const char* __restrict__ Kp,
                                         const char* __restrict__ Vt, int kv0,
                                         int tid) {
  const int wave = tid >> 6;
#pragma unroll
  for (int j = 0; j < 2; ++j) {
    int d = j * 256 + tid;  // chunk id 0..511
    int row = d >> 3, cc = d & 7;
    int gc = cc ^ (row & 7);
    const char* gk = Kp + (size_t)kv0 * 128 + row * 128 + gc * 16;
    async_copy16(Kb + (j * 256 + wave * 64) * 16, gk);
    const char* gv = Vt + (size_t)row * 4096 + (size_t)kv0 * 2 + gc * 16;
    async_copy16(Vb + (j * 256 + wave * 64) * 16, gv);
  }
}

// read a 32x16 fragment row slice from a swizzled [64][128B] LDS tile
__device__ __forceinline__ short8 read_frag(const char* __restrict__ base, int row,
                                            int chunk) {
  return *(const short8*)(base + row * 128 + ((chunk ^ (row & 7)) * 16));
}

__device__ __forceinline__ void attn_step(
    const char* __restrict__ Kb, const char* __restrict__ Vb,
    const short8 (&qf)[4], int kv0, int q0, int l31, int hi, bool diag,
    float& m_i, floatx16& accL, floatx16 (&accO)[2]) {
  // ---- QK^T (swapped): S^T[kv][q], two 32-kv halves ----
  floatx16 sh[2];
  __builtin_amdgcn_s_setprio(1);
#pragma unroll
  for (int hh = 0; hh < 2; ++hh) {
    floatx16 a;
#pragma unroll
    for (int e = 0; e < 16; ++e) a[e] = 0.f;
#pragma unroll
    for (int ks = 0; ks < 4; ++ks) {
      short8 kf = read_frag(Kb, hh * 32 + l31, 2 * ks + hi);
      a = __builtin_amdgcn_mfma_f32_32x32x16_bf16(kf, qf[ks], a, 0, 0, 0);
    }
    sh[hh] = a;
  }
  __builtin_amdgcn_s_setprio(0);

  const int q = q0 + l31;
  if (diag) {
#pragma unroll
    for (int hh = 0; hh < 2; ++hh)
#pragma unroll
      for (int r = 0; r < 16; ++r) {
        int kvi = kv0 + 32 * hh + (r & 3) + 8 * (r >> 2) + 4 * hi;
        if (kvi > q) sh[hh][r] = -1e30f;
      }
  }

  // ---- in-lane max over this lane's 32 values ----
  float t[11];
#pragma unroll
  for (int i = 0; i < 10; ++i)
    t[i] = max3f(sh[(3 * i) / 16][(3 * i) % 16], sh[(3 * i + 1) / 16][(3 * i + 1) % 16],
                 sh[(3 * i + 2) / 16][(3 * i + 2) % 16]);
  t[10] = fmaxf(sh[1][14], sh[1][15]);
  float pmax = max3f(max3f(t[0], t[1], t[2]), max3f(t[3], t[4], t[5]),
                     max3f(t[6], t[7], t[8]));
  pmax = max3f(pmax, t[9], t[10]);

  // defer-max (kv-half lane pair covered by __any + shfl)
  if (__any(pmax > m_i + 11.5f)) {
    float mx = fmaxf(pmax, __shfl_xor(pmax, 32));
    float mnew = fmaxf(m_i, mx);
    float scl = exp2f(m_i - mnew);
    m_i = mnew;
    accL[0] *= scl;  // only elem 0 is ever read
#pragma unroll
    for (int dt = 0; dt < 2; ++dt)
#pragma unroll
      for (int r = 0; r < 16; ++r) accO[dt][r] *= scl;
  }

  // ---- P = exp2(S - m) ----
  float p[32];
#pragma unroll
  for (int hh = 0; hh < 2; ++hh)
#pragma unroll
    for (int r = 0; r < 16; ++r) p[hh * 16 + r] = exp2f(sh[hh][r] - m_i);

  // ---- P -> B-fragments via cvt_pk + permlane32_swap ----
  short8 pb[4];
#pragma unroll
  for (int ks2 = 0; ks2 < 4; ++ks2) {
    const int ib = (ks2 >> 1) * 16 + (ks2 & 1) * 8;
    unsigned int a0 = cvt_pk_bf16(p[ib + 0], p[ib + 1]);
    unsigned int b0 = cvt_pk_bf16(p[ib + 4], p[ib + 5]);
    unsigned int a1 = cvt_pk_bf16(p[ib + 2], p[ib + 3]);
    unsigned int b1 = cvt_pk_bf16(p[ib + 6], p[ib + 7]);
    asm volatile("v_permlane32_swap_b32 %0, %1" : "+v"(a0), "+v"(b0));
    asm volatile("v_permlane32_swap_b32 %0, %1" : "+v"(a1), "+v"(b1));
    unsigned int w[4] = {a0, a1, b0, b1};
    pb[ks2] = *(const short8*)w;
  }

  short8 ones;
#pragma unroll
  for (int j = 0; j < 8; ++j) ones[j] = (short)0x3F80;

  // ---- PV: O^T[d][q] = mfma32(Vt-tile, P^T); l via mfma32(ones, P^T) ----
  __builtin_amdgcn_s_setprio(1);
#pragma unroll
  for (int ks2 = 0; ks2 < 4; ++ks2) {
#pragma unroll
    for (int dt = 0; dt < 2; ++dt) {
      short8 vf = read_frag(Vb, dt * 32 + l31, 2 * ks2 + hi);
      accO[dt] = __builtin_amdgcn_mfma_f32_32x32x16_bf16(vf, pb[ks2], accO[dt], 0, 0, 0);
    }
    accL = __builtin_amdgcn_mfma_f32_32x32x16_bf16(ones, pb[ks2], accL, 0, 0, 0);
  }
  __builtin_amdgcn_s_setprio(0);
}

__global__ __launch_bounds__(256, 3) void attn_fwd(
    const unsigned short* __restrict__ qb, const unsigned short* __restrict__ kb,
    const unsigned short* __restrict__ vtb, unsigned short* __restrict__ ob) {
  __shared__ __align__(16) char Kbuf[2][8192];
  __shared__ __align__(16) char Vbuf[2][8192];

  // id = (15-qt)*64 + bh : LPT order; xcd = bh%8 keeps head L2 locality.
  const int id = blockIdx.x;
  const int qt = 15 - (id >> 6);
  const int bh = id & 63;

  const int tid = threadIdx.x;
  const int wave = tid >> 6, lane = tid & 63;
  const int l31 = lane & 31, hi = lane >> 5;
  const unsigned short* Q = qb + (long)bh * 2048 * 64;
  const char* Kp = (const char*)(kb + (long)bh * 2048 * 64);
  const char* Vt = (const char*)(vtb + (long)bh * 64 * 2048);
  const int b = bh >> 4, h = bh & 15;

  const int q0 = qt * 128 + wave * 32;  // this wave's 32 q-rows
  const int nkv = 2 * qt + 2;

  // Q B-fragments: col q = q0+l31, k = ks*16 + hi*8 + j
  short8 qf[4];
#pragma unroll
  for (int ks = 0; ks < 4; ++ks)
    qf[ks] = *(const short8*)(Q + (q0 + l31) * 64 + ks * 16 + hi * 8);

  floatx16 accO[2];
  floatx16 accL;
#pragma unroll
  for (int e = 0; e < 16; ++e) {
    accO[0][e] = 0.f;
    accO[1][e] = 0.f;
    accL[e] = 0.f;
  }
  float m_i = -1e30f;

  stage_kv(Kbuf[0], Vbuf[0], Kp, Vt, 0, tid);
  __syncthreads();
#pragma unroll 1
  for (int kv = 0; kv < nkv; ++kv) {
    if (kv + 1 < nkv)
      stage_kv(Kbuf[(kv + 1) & 1], Vbuf[(kv + 1) & 1], Kp, Vt, (kv + 1) * 64, tid);
    const int kv0 = kv * 64;
    if (kv0 < q0 + 32)  // skip tiles fully above this wave's rows
      attn_step(Kbuf[kv & 1], Vbuf[kv & 1], qf, kv0, q0, l31, hi,
                kv0 + 64 > q0, m_i, accL, accO);
    __syncthreads();
  }

  // epilogue: accL[0] is the complete l for q = q0+l31 (lane-local)
  float io = 1.f / accL[0];
  const int q = q0 + l31;
  unsigned short* orow = ob + ((long)b * 2048 + q) * 1024 + h * 64;
#pragma unroll
  for (int dt = 0; dt < 2; ++dt)
#pragma unroll
    for (int g = 0; g < 4; ++g) {
      short4v pk;
#pragma unroll
      for (int e = 0; e < 4; ++e) pk[e] = (short)f2bf(accO[dt][4 * g + e] * io);
      *(short4v*)(orow + dt * 32 + g * 8 + hi * 4) = pk;
    }
}

// ---------------------------------------------------------------------------
extern "C" void kernel_launch(void* const* d_in, const int* in_sizes, int n_in,
                              void* d_out, int out_size, void* d_ws, size_t ws_size,
                              hipStream_t stream) {
  const float* x = (const float*)d_in[0];
  const float* bq = (const float*)d_in[2];
  const float* bk = (const float*)d_in[4];
  const float* bv = (const float*)d_in[6];
  const float* bo = (const float*)d_in[8];
  float* out = (float*)d_out;

  char* ws = (char*)d_ws;
  unsigned short* xb = (unsigned short*)(ws);                  // 16 MB  [8192][1024]
  unsigned short* wqkv = (unsigned short*)(ws + (16l << 20));  // 6 MB   [3072][1024]
  unsigned short* wob = (unsigned short*)(ws + (22l << 20));   // 2 MB   [1024][1024]
  unsigned short* qb = (unsigned short*)(ws + (24l << 20));    // 16 MB  [64][2048][64]
  unsigned short* kb = (unsigned short*)(ws + (40l << 20));    // 16 MB  [64][2048][64]
  unsigned short* vtb = (unsigned short*)(ws + (56l << 20));   // 16 MB  [64][64][2048]
  unsigned short* ob = (unsigned short*)(ws + (72l << 20));    // 16 MB  [8192][1024]

  f2ball_kernel<<<12288, 256, 0, stream>>>(
      x, xb, (const float*)d_in[1], (const float*)d_in[3], (const float*)d_in[5],
      (const float*)d_in[7], wqkv, wqkv + (1l << 20), wqkv + (2l << 20), wob);

  qkv_gemm256<<<dim3(64, 12), 256, 0, stream>>>(xb, wqkv, bq, bk, bv, qb, kb, vtb);
  attn_fwd<<<1024, 256, 0, stream>>>(qb, kb, vtb, ob);
  out_gemm256<<<dim3(64, 4), 256, 0, stream>>>(ob, wob, bo, out);
}

// Round 21
// 162.950 us; speedup vs baseline: 1.0145x; 1.0145x over previous
//
#include <hip/hip_runtime.h>
#include <stdint.h>

typedef __attribute__((ext_vector_type(8))) short short8;
typedef __attribute__((ext_vector_type(4))) short short4v;
typedef __attribute__((ext_vector_type(4))) float floatx4;
typedef __attribute__((ext_vector_type(16))) float floatx16;

#define QSCALE 0.1803368801111f /* 0.125 * log2(e): S in log2 units */

__device__ __forceinline__ unsigned short f2bf(float f) {
  unsigned int u = __float_as_uint(f);
  unsigned int r = (u + 0x7FFFu + ((u >> 16) & 1u)) >> 16;  // RNE
  return (unsigned short)r;
}

__device__ __forceinline__ unsigned int cvt_pk_bf16(float lo, float hi) {
  unsigned int r;
  asm("v_cvt_pk_bf16_f32 %0, %1, %2" : "=v"(r) : "v"(lo), "v"(hi));
  return r;
}

__device__ __forceinline__ float max3f(float a, float b, float c) {
  float r;
  asm("v_max3_f32 %0, %1, %2, %3" : "=v"(r) : "v"(a), "v"(b), "v"(c));
  return r;
}

__device__ __forceinline__ void async_copy16(void* lds, const void* g) {
  __builtin_amdgcn_global_load_lds(
      (const __attribute__((address_space(1))) unsigned int*)g,
      (__attribute__((address_space(3))) unsigned int*)lds, 16, 0, 0);
}

// ---------------------------------------------------------------------------
// ALL fp32 -> bf16 conversions in one launch.
// ---------------------------------------------------------------------------
__global__ __launch_bounds__(256) void f2ball_kernel(
    const float* __restrict__ x, unsigned short* __restrict__ xb,
    const float* __restrict__ w0, const float* __restrict__ w1,
    const float* __restrict__ w2, const float* __restrict__ w3,
    unsigned short* __restrict__ o0, unsigned short* __restrict__ o1,
    unsigned short* __restrict__ o2, unsigned short* __restrict__ o3) {
  const float* in;
  unsigned short* out;
  long i;
  if (blockIdx.x < 8192) {
    in = x;
    out = xb;
    i = (long)blockIdx.x * 256 + threadIdx.x;
  } else {
    int wb = blockIdx.x - 8192;
    int which = wb >> 10;
    in = (which == 0) ? w0 : (which == 1) ? w1 : (which == 2) ? w2 : w3;
    out = (which == 0) ? o0 : (which == 1) ? o1 : (which == 2) ? o2 : o3;
    i = (long)(wb & 1023) * 256 + threadIdx.x;
  }
  float4 v = ((const float4*)in)[i];
  short4v o;
  o[0] = (short)f2bf(v.x);
  o[1] = (short)f2bf(v.y);
  o[2] = (short)f2bf(v.z);
  o[3] = (short)f2bf(v.w);
  *(short4v*)(out + i * 4) = o;
}

// ---------------------------------------------------------------------------
// Double-buffered 2-phase GEMM mainloop, 128x128 (out_gemm).
// ---------------------------------------------------------------------------
__device__ __forceinline__ void gemm128_mainloop_db(
    const unsigned short* __restrict__ A, const unsigned short* __restrict__ Bt,
    int K, long brow, long bcol, unsigned short* As, unsigned short* Bs,
    floatx4 acc[4][4]) {
  const int tid = threadIdx.x;
  const int wave = tid >> 6;
  const int lane = tid & 63;
  const int wr = wave >> 1, wc = wave & 1;
  const int lr = lane & 15, lg = lane >> 4;

  const unsigned short* ga = A + (brow + (tid >> 2)) * (long)K + (tid & 3) * 8;
  const unsigned short* gb = Bt + (bcol + (tid >> 2)) * (long)K + (tid & 3) * 8;
  const int woff = wave * 512;
  const int a_off = (wr * 64 + lr) * 32 + lg * 8;
  const int b_off = (wc * 64 + lr) * 32 + lg * 8;

  async_copy16(As + woff, ga);
  async_copy16(As + woff + 2048, ga + (long)64 * K);
  async_copy16(Bs + woff, gb);
  async_copy16(Bs + woff + 2048, gb + (long)64 * K);
  ga += 32;
  gb += 32;
  __syncthreads();

  int buf = 0;
  for (int kt = 0; kt < K; kt += 32) {
    if (kt + 32 < K) {
      unsigned short* lA = As + (buf ^ 1) * 4096 + woff;
      unsigned short* lB = Bs + (buf ^ 1) * 4096 + woff;
      async_copy16(lA, ga);
      async_copy16(lA + 2048, ga + (long)64 * K);
      async_copy16(lB, gb);
      async_copy16(lB + 2048, gb + (long)64 * K);
      ga += 32;
      gb += 32;
    }
    const unsigned short* Ab = As + buf * 4096;
    const unsigned short* Bb = Bs + buf * 4096;
    short8 af[4], bf[4];
#pragma unroll
    for (int i = 0; i < 4; ++i) {
      af[i] = *(const short8*)(Ab + a_off + i * 512);
      bf[i] = *(const short8*)(Bb + b_off + i * 512);
    }
#pragma unroll
    for (int i = 0; i < 4; ++i)
#pragma unroll
      for (int j = 0; j < 4; ++j)
        acc[i][j] = __builtin_amdgcn_mfma_f32_16x16x32_bf16(af[i], bf[j], acc[i][j], 0, 0, 0);
    __syncthreads();
    buf ^= 1;
  }
}

// ===========================================================================
// 128x256 double-buffered GEMM mainloop (qkv256).
// ===========================================================================
__device__ __forceinline__ void gemm256_mainloop(
    const unsigned short* __restrict__ A, const unsigned short* __restrict__ Bt,
    long brow, long bcol, unsigned short* As, unsigned short* Bs,
    floatx4 acc[4][8]) {
  const int tid = threadIdx.x;
  const int wave = tid >> 6, lane = tid & 63;
  const int wr = wave >> 1, wc = wave & 1;
  const int lr = lane & 15, lg = lane >> 4;
  const int K = 1024;

  const unsigned short* ga = A + (brow + (tid >> 2)) * (long)K + (tid & 3) * 8;
  const unsigned short* gb = Bt + (bcol + (tid >> 2)) * (long)K + (tid & 3) * 8;
  const int woff = wave * 512;
  const int a_off = (wr * 64 + lr) * 32 + lg * 8;
  const int b_off = (wc * 128 + lr) * 32 + lg * 8;

  async_copy16(As + woff, ga);
  async_copy16(As + woff + 2048, ga + (long)64 * K);
#pragma unroll
  for (int jj = 0; jj < 4; ++jj)
    async_copy16(Bs + woff + jj * 2048, gb + (long)jj * 64 * K);
  ga += 32;
  gb += 32;
  __syncthreads();

  int buf = 0;
  for (int kt = 0; kt < K; kt += 32) {
    if (kt + 32 < K) {
      unsigned short* lA = As + (buf ^ 1) * 4096 + woff;
      unsigned short* lB = Bs + (buf ^ 1) * 8192 + woff;
      async_copy16(lA, ga);
      async_copy16(lA + 2048, ga + (long)64 * K);
#pragma unroll
      for (int jj = 0; jj < 4; ++jj)
        async_copy16(lB + jj * 2048, gb + (long)jj * 64 * K);
      ga += 32;
      gb += 32;
    }
    const unsigned short* Ab = As + buf * 4096;
    const unsigned short* Bb = Bs + buf * 8192;
    short8 av[4], bvf[8];
#pragma unroll
    for (int i = 0; i < 4; ++i) av[i] = *(const short8*)(Ab + a_off + i * 512);
#pragma unroll
    for (int j = 0; j < 8; ++j) bvf[j] = *(const short8*)(Bb + b_off + j * 512);
    __builtin_amdgcn_s_setprio(1);
#pragma unroll
    for (int i = 0; i < 4; ++i)
#pragma unroll
      for (int j = 0; j < 8; ++j)
        acc[i][j] = __builtin_amdgcn_mfma_f32_16x16x32_bf16(av[i], bvf[j], acc[i][j], 0, 0, 0);
    __builtin_amdgcn_s_setprio(0);
    __syncthreads();
    buf ^= 1;
  }
}

// ---------------------------------------------------------------------------
// QKV projection, 128x256 tile. Q pre-scaled to log2 units; V-epilogue
// transposes via LDS in two 128-col halves. Grid (64,12), 48 KB LDS.
// ---------------------------------------------------------------------------
__global__ __launch_bounds__(256, 2) void qkv_gemm256(
    const unsigned short* __restrict__ xb, const unsigned short* __restrict__ wqkv,
    const float* __restrict__ bq, const float* __restrict__ bk,
    const float* __restrict__ bv, unsigned short* __restrict__ q_out,
    unsigned short* __restrict__ k_out, unsigned short* __restrict__ vt_out) {
  __shared__ __align__(16) unsigned short Sh[24576];  // 48 KB
  unsigned short* As = Sh;
  unsigned short* Bs = Sh + 8192;

  const int tid = threadIdx.x;
  const int wave = tid >> 6, lane = tid & 63;
  const int wr = wave >> 1, wc = wave & 1;
  const int lr = lane & 15, lg = lane >> 4;

  const long brow = (long)blockIdx.x * 128;
  const long bcol = (long)blockIdx.y * 256;

  floatx4 zero = {0.f, 0.f, 0.f, 0.f};
  floatx4 acc[4][8];
#pragma unroll
  for (int i = 0; i < 4; ++i)
#pragma unroll
    for (int j = 0; j < 8; ++j) acc[i][j] = zero;

  gemm256_mainloop(xb, wqkv, brow, bcol, As, Bs, acc);

  const int kind = (int)(bcol >> 10);
  const float* bias = (kind == 0) ? bq : (kind == 1 ? bk : bv);

  if (kind == 2) {
#pragma unroll 1
    for (int half = 0; half < 2; ++half) {
      if (wc == half) {
#pragma unroll
        for (int i = 0; i < 4; ++i)
#pragma unroll
          for (int j = 0; j < 8; ++j) {
            int n_local = j * 16 + lr;
            int m_base = wr * 64 + i * 16 + lg * 4;
            float bsc = bias[(int)((bcol + half * 128 + n_local) & 1023)];
            short4v pk;
#pragma unroll
            for (int r = 0; r < 4; ++r) pk[r] = (short)f2bf(acc[i][j][r] + bsc);
            *(short4v*)(Sh + n_local * 136 + m_base) = pk;
          }
      }
      __syncthreads();
      const int b = (int)(brow >> 11);
      const int t0 = (int)(brow & 2047);
      const int f0h = (int)(bcol - 2048) + half * 128;
#pragma unroll
      for (int p = 0; p < 8; ++p) {
        int c = p * 256 + tid;
        int d_loc = c >> 4, tc = c & 15;
        short8 v = *(const short8*)(Sh + d_loc * 136 + tc * 8);
        int h = (f0h >> 6) + (d_loc >> 6);
        int d = d_loc & 63;
        *(short8*)(vt_out + ((long)((b * 16 + h) * 64 + d)) * 2048 + t0 + tc * 8) = v;
      }
      __syncthreads();
    }
  } else {
#pragma unroll
    for (int i = 0; i < 4; ++i)
#pragma unroll
      for (int j = 0; j < 8; ++j)
#pragma unroll
        for (int r = 0; r < 4; ++r) {
          int m = (int)brow + wr * 64 + i * 16 + lg * 4 + r;
          int n = (int)bcol + wc * 128 + j * 16 + lr;
          int f = n & 1023;
          float v = acc[i][j][r] + bias[f];
          if (kind == 0) v *= QSCALE;
          unsigned short o = f2bf(v);
          int h = f >> 6, d = f & 63;
          int bb = m >> 11, t = m & 2047;
          long bh = (long)(bb * 16 + h);
          if (kind == 0)
            q_out[(bh * 2048 + t) * 64 + d] = o;
          else
            k_out[(bh * 2048 + t) * 64 + d] = o;
        }
  }
}

// ---------------------------------------------------------------------------
// Output projection (128x128)
// ---------------------------------------------------------------------------
__global__ __launch_bounds__(256, 4) void out_gemm(
    const unsigned short* __restrict__ ob, const unsigned short* __restrict__ wo,
    const float* __restrict__ bo, float* __restrict__ out) {
  __shared__ unsigned short As[2 * 128 * 32];
  __shared__ unsigned short Bs[2 * 128 * 32];
  floatx4 zero = {0.f, 0.f, 0.f, 0.f};
  floatx4 acc[4][4];
#pragma unroll
  for (int i = 0; i < 4; ++i)
#pragma unroll
    for (int j = 0; j < 4; ++j) acc[i][j] = zero;

  long brow = (long)blockIdx.x * 128;
  long bcol = (long)blockIdx.y * 128;
  gemm128_mainloop_db(ob, wo, 1024, brow, bcol, As, Bs, acc);

  const int wave = threadIdx.x >> 6, lane = threadIdx.x & 63;
  const int wr = wave >> 1, wc = wave & 1, lr = lane & 15, lg = lane >> 4;
#pragma unroll
  for (int i = 0; i < 4; ++i)
#pragma unroll
    for (int j = 0; j < 4; ++j)
#pragma unroll
      for (int r = 0; r < 4; ++r) {
        int m = (int)brow + wr * 64 + i * 16 + lg * 4 + r;
        int n = (int)bcol + wc * 64 + j * 16 + lr;
        out[(long)m * 1024 + n] = acc[i][j][r] + bo[n];
      }
}

// ---------------------------------------------------------------------------
// Flash attention v13: 4 waves x 32 q-rows, 32x32 swapped-QK in-register
// softmax, KVBLK=64 dbuf (32 KB LDS), l-via-MFMA(ones), 1024-block LPT grid.
// ---------------------------------------------------------------------------
__device__ __forceinline__ void stage_kv(char* __restrict__ Kb, char* __restrict__ Vb,
                                         const char* __restrict__ Kp,
                                         const char* __restrict__ Vt, int kv0,
                                         int tid) {
  const int wave = tid >> 6;
#pragma unroll
  for (int j = 0; j < 2; ++j) {
    int d = j * 256 + tid;  // chunk id 0..511
    int row = d >> 3, cc = d & 7;
    int gc = cc ^ (row & 7);
    const char* gk = Kp + (size_t)kv0 * 128 + row * 128 + gc * 16;
    async_copy16(Kb + (j * 256 + wave * 64) * 16, gk);
    const char* gv = Vt + (size_t)row * 4096 + (size_t)kv0 * 2 + gc * 16;
    async_copy16(Vb + (j * 256 + wave * 64) * 16, gv);
  }
}

// read a 32x16 fragment row slice from a swizzled [64][128B] LDS tile
__device__ __forceinline__ short8 read_frag(const char* __restrict__ base, int row,
                                            int chunk) {
  return *(const short8*)(base + row * 128 + ((chunk ^ (row & 7)) * 16));
}

__device__ __forceinline__ void attn_step(
    const char* __restrict__ Kb, const char* __restrict__ Vb,
    const short8 (&qf)[4], int kv0, int q0, int l31, int hi, bool diag,
    float& m_i, floatx16& accL, floatx16 (&accO)[2]) {
  // ---- QK^T (swapped): S^T[kv][q], two 32-kv halves ----
  floatx16 sh[2];
  __builtin_amdgcn_s_setprio(1);
#pragma unroll
  for (int hh = 0; hh < 2; ++hh) {
    floatx16 a;
#pragma unroll
    for (int e = 0; e < 16; ++e) a[e] = 0.f;
#pragma unroll
    for (int ks = 0; ks < 4; ++ks) {
      short8 kf = read_frag(Kb, hh * 32 + l31, 2 * ks + hi);
      a = __builtin_amdgcn_mfma_f32_32x32x16_bf16(kf, qf[ks], a, 0, 0, 0);
    }
    sh[hh] = a;
  }
  __builtin_amdgcn_s_setprio(0);

  const int q = q0 + l31;
  if (diag) {
#pragma unroll
    for (int hh = 0; hh < 2; ++hh)
#pragma unroll
      for (int r = 0; r < 16; ++r) {
        int kvi = kv0 + 32 * hh + (r & 3) + 8 * (r >> 2) + 4 * hi;
        if (kvi > q) sh[hh][r] = -1e30f;
      }
  }

  // ---- in-lane max over this lane's 32 values ----
  float t[11];
#pragma unroll
  for (int i = 0; i < 10; ++i)
    t[i] = max3f(sh[(3 * i) / 16][(3 * i) % 16], sh[(3 * i + 1) / 16][(3 * i + 1) % 16],
                 sh[(3 * i + 2) / 16][(3 * i + 2) % 16]);
  t[10] = fmaxf(sh[1][14], sh[1][15]);
  float pmax = max3f(max3f(t[0], t[1], t[2]), max3f(t[3], t[4], t[5]),
                     max3f(t[6], t[7], t[8]));
  pmax = max3f(pmax, t[9], t[10]);

  // defer-max (kv-half lane pair covered by __any + shfl)
  if (__any(pmax > m_i + 11.5f)) {
    float mx = fmaxf(pmax, __shfl_xor(pmax, 32));
    float mnew = fmaxf(m_i, mx);
    float scl = exp2f(m_i - mnew);
    m_i = mnew;
    accL[0] *= scl;  // only elem 0 is ever read
#pragma unroll
    for (int dt = 0; dt < 2; ++dt)
#pragma unroll
      for (int r = 0; r < 16; ++r) accO[dt][r] *= scl;
  }

  // ---- P = exp2(S - m) ----
  float p[32];
#pragma unroll
  for (int hh = 0; hh < 2; ++hh)
#pragma unroll
    for (int r = 0; r < 16; ++r) p[hh * 16 + r] = exp2f(sh[hh][r] - m_i);

  // ---- P -> B-fragments via cvt_pk + permlane32_swap ----
  short8 pb[4];
#pragma unroll
  for (int ks2 = 0; ks2 < 4; ++ks2) {
    const int ib = (ks2 >> 1) * 16 + (ks2 & 1) * 8;
    unsigned int a0 = cvt_pk_bf16(p[ib + 0], p[ib + 1]);
    unsigned int b0 = cvt_pk_bf16(p[ib + 4], p[ib + 5]);
    unsigned int a1 = cvt_pk_bf16(p[ib + 2], p[ib + 3]);
    unsigned int b1 = cvt_pk_bf16(p[ib + 6], p[ib + 7]);
    asm volatile("v_permlane32_swap_b32 %0, %1" : "+v"(a0), "+v"(b0));
    asm volatile("v_permlane32_swap_b32 %0, %1" : "+v"(a1), "+v"(b1));
    unsigned int w[4] = {a0, a1, b0, b1};
    pb[ks2] = *(const short8*)w;
  }

  short8 ones;
#pragma unroll
  for (int j = 0; j < 8; ++j) ones[j] = (short)0x3F80;

  // ---- PV: O^T[d][q] = mfma32(Vt-tile, P^T); l via mfma32(ones, P^T) ----
  __builtin_amdgcn_s_setprio(1);
#pragma unroll
  for (int ks2 = 0; ks2 < 4; ++ks2) {
#pragma unroll
    for (int dt = 0; dt < 2; ++dt) {
      short8 vf = read_frag(Vb, dt * 32 + l31, 2 * ks2 + hi);
      accO[dt] = __builtin_amdgcn_mfma_f32_32x32x16_bf16(vf, pb[ks2], accO[dt], 0, 0, 0);
    }
    accL = __builtin_amdgcn_mfma_f32_32x32x16_bf16(ones, pb[ks2], accL, 0, 0, 0);
  }
  __builtin_amdgcn_s_setprio(0);
}

__global__ __launch_bounds__(256, 3) void attn_fwd(
    const unsigned short* __restrict__ qb, const unsigned short* __restrict__ kb,
    const unsigned short* __restrict__ vtb, unsigned short* __restrict__ ob) {
  __shared__ __align__(16) char Kbuf[2][8192];
  __shared__ __align__(16) char Vbuf[2][8192];

  // id = (15-qt)*64 + bh : LPT order; xcd = bh%8 keeps head L2 locality.
  const int id = blockIdx.x;
  const int qt = 15 - (id >> 6);
  const int bh = id & 63;

  const int tid = threadIdx.x;
  const int wave = tid >> 6, lane = tid & 63;
  const int l31 = lane & 31, hi = lane >> 5;
  const unsigned short* Q = qb + (long)bh * 2048 * 64;
  const char* Kp = (const char*)(kb + (long)bh * 2048 * 64);
  const char* Vt = (const char*)(vtb + (long)bh * 64 * 2048);
  const int b = bh >> 4, h = bh & 15;

  const int q0 = qt * 128 + wave * 32;  // this wave's 32 q-rows
  const int nkv = 2 * qt + 2;

  // Q B-fragments: col q = q0+l31, k = ks*16 + hi*8 + j
  short8 qf[4];
#pragma unroll
  for (int ks = 0; ks < 4; ++ks)
    qf[ks] = *(const short8*)(Q + (q0 + l31) * 64 + ks * 16 + hi * 8);

  floatx16 accO[2];
  floatx16 accL;
#pragma unroll
  for (int e = 0; e < 16; ++e) {
    accO[0][e] = 0.f;
    accO[1][e] = 0.f;
    accL[e] = 0.f;
  }
  float m_i = -1e30f;

  stage_kv(Kbuf[0], Vbuf[0], Kp, Vt, 0, tid);
  __syncthreads();
#pragma unroll 1
  for (int kv = 0; kv < nkv; ++kv) {
    if (kv + 1 < nkv)
      stage_kv(Kbuf[(kv + 1) & 1], Vbuf[(kv + 1) & 1], Kp, Vt, (kv + 1) * 64, tid);
    const int kv0 = kv * 64;
    if (kv0 < q0 + 32)  // skip tiles fully above this wave's rows
      attn_step(Kbuf[kv & 1], Vbuf[kv & 1], qf, kv0, q0, l31, hi,
                kv0 + 64 > q0, m_i, accL, accO);
    __syncthreads();
  }

  // epilogue: accL[0] is the complete l for q = q0+l31 (lane-local)
  float io = 1.f / accL[0];
  const int q = q0 + l31;
  unsigned short* orow = ob + ((long)b * 2048 + q) * 1024 + h * 64;
#pragma unroll
  for (int dt = 0; dt < 2; ++dt)
#pragma unroll
    for (int g = 0; g < 4; ++g) {
      short4v pk;
#pragma unroll
      for (int e = 0; e < 4; ++e) pk[e] = (short)f2bf(accO[dt][4 * g + e] * io);
      *(short4v*)(orow + dt * 32 + g * 8 + hi * 4) = pk;
    }
}

// ---------------------------------------------------------------------------
extern "C" void kernel_launch(void* const* d_in, const int* in_sizes, int n_in,
                              void* d_out, int out_size, void* d_ws, size_t ws_size,
                              hipStream_t stream) {
  const float* x = (const float*)d_in[0];
  const float* bq = (const float*)d_in[2];
  const float* bk = (const float*)d_in[4];
  const float* bv = (const float*)d_in[6];
  const float* bo = (const float*)d_in[8];
  float* out = (float*)d_out;

  char* ws = (char*)d_ws;
  unsigned short* xb = (unsigned short*)(ws);                  // 16 MB  [8192][1024]
  unsigned short* wqkv = (unsigned short*)(ws + (16l << 20));  // 6 MB   [3072][1024]
  unsigned short* wob = (unsigned short*)(ws + (22l << 20));   // 2 MB   [1024][1024]
  unsigned short* qb = (unsigned short*)(ws + (24l << 20));    // 16 MB  [64][2048][64]
  unsigned short* kb = (unsigned short*)(ws + (40l << 20));    // 16 MB  [64][2048][64]
  unsigned short* vtb = (unsigned short*)(ws + (56l << 20));   // 16 MB  [64][64][2048]
  unsigned short* ob = (unsigned short*)(ws + (72l << 20));    // 16 MB  [8192][1024]

  f2ball_kernel<<<12288, 256, 0, stream>>>(
      x, xb, (const float*)d_in[1], (const float*)d_in[3], (const float*)d_in[5],
      (const float*)d_in[7], wqkv, wqkv + (1l << 20), wqkv + (2l << 20), wob);

  qkv_gemm256<<<dim3(64, 12), 256, 0, stream>>>(xb, wqkv, bq, bk, bv, qb, kb, vtb);
  attn_fwd<<<1024, 256, 0, stream>>>(qb, kb, vtb, ob);
  out_gemm<<<dim3(64, 8), 256, 0, stream>>>(ob, wob, bo, out);
}